// Round 6
// baseline (188.252 us; speedup 1.0000x reference)
//
#include <hip/hip_runtime.h>

// GuidedCnn: fused offset-conv (8ch -> 18ch, 3x3) + deformable conv.
// R6: LDS-pipe diet. (1) MFMA B-fragments built from global (L1-hot) instead
// of LDS; (2) pf sampling tile channel-interleaved [pix][4] so stage-2
// bilinear corners are single ds_read_b128; (3) divergent A-frag assembly
// (hi quads read 1 tap, not 9). R5 was LDS-unit-bound (~390 LDS ops/lane,
// 8.9M bank-conflict cycles).

#define Bn 8
#define Hn 384
#define Wn 384
#define HWn (Hn * Wn)
#define TILE 16
#define PH 8
#define PT 32                  // sampling tile extent (halo 8)
#define CSTR 33                // conv tile row stride (odd: conflict-free)
#define CPL (18 * CSTR)        // 594 floats per conv-tile channel

// LDS float-offset map
#define OFF_PTILE 0
#define SZ_PTILE (PT * PT * 4)           // 4096 floats, [pix][ch0..2,pad]
#define OFF_T8   SZ_PTILE
#define SZ_T8U   4864                    // max(8*CPL=4752, offb 256*19=4864)
#define SMEM_FLOATS (OFF_T8 + SZ_T8U)    // 8960 floats = 35,840 B

typedef float f32x4 __attribute__((ext_vector_type(4)));
typedef short s16x8 __attribute__((ext_vector_type(8)));

__device__ inline unsigned pack_bf16(float lo, float hi) {
    // truncation pack (matches R5 accuracy: absmax 0.0156 vs 0.0459 thr)
    return (__float_as_uint(hi) & 0xffff0000u) | (__float_as_uint(lo) >> 16);
}
__device__ inline unsigned short rne_bf16(float f) {
    unsigned u = __float_as_uint(f);
    u += 0x7fffu + ((u >> 16) & 1u);
    return (unsigned short)(u >> 16);
}

__global__ __launch_bounds__(256, 4) void guided_cnn_fused(
    const float* __restrict__ pf, const float* __restrict__ cf,
    const float* __restrict__ mv, const float* __restrict__ ow,
    const float* __restrict__ ob, const float* __restrict__ dw,
    float* __restrict__ out)
{
    __shared__ float smem[SMEM_FLOATS];

    const int tid = threadIdx.x;
    const int b = blockIdx.z;
    const int tileY0 = blockIdx.y * TILE;
    const int tileX0 = blockIdx.x * TILE;
    const int oy = tileY0 - PH;
    const int ox = tileX0 - PH;

    float* ptile4 = smem + OFF_PTILE;
    float* t8     = smem + OFF_T8;

    const int lane  = tid & 63;
    const int wv    = tid >> 6;
    const int am    = lane & 15;       // A row (pixel tx); also B col
    const int g     = lane >> 4;       // quad 0..3
    const bool hiK  = (g & 1);
    const int chalf = lane >> 5;

    // ---- B-fragments from global (no LDS): lane holds B[k=32s+8g+j][n] ----
    s16x8 bfrag[4][2];
#pragma unroll
    for (int s = 0; s < 4; ++s) {
#pragma unroll
        for (int nt = 0; nt < 2; ++nt) {
            const int oc = nt * 16 + am;
            const bool ocok = (oc < 18);
            const int occ = ocok ? oc : 17;
            union { unsigned short h[8]; s16x8 v; } F;
#pragma unroll
            for (int j = 0; j < 8; ++j) {
                const int k = 32 * s + 8 * g + j;
                const int c = k >> 4;
                const int t = k & 15;
                const bool valid = (t < 9) && ocok;
                const float w = ow[occ * 72 + c * 9 + (t < 9 ? t : 8)];
                F.h[j] = valid ? rne_bf16(w) : (unsigned short)0;
            }
            bfrag[s][nt] = F.v;
        }
    }

    // ---- stage ptile4: pf 3ch interleaved [pix][4], b128 writes ----
    for (int p = tid; p < PT * PT; p += 256) {
        const int row = p >> 5;
        const int col = p & 31;
        const int gy = oy + row, gx = ox + col;
        const bool v = ((unsigned)gy < (unsigned)Hn) && ((unsigned)gx < (unsigned)Wn);
        const size_t gidx = (size_t)b * 3 * HWn + gy * Wn + gx;
        f32x4 q;
        q[0] = v ? pf[gidx] : 0.f;
        q[1] = v ? pf[gidx + HWn] : 0.f;
        q[2] = v ? pf[gidx + 2 * HWn] : 0.f;
        q[3] = 0.f;
        *(f32x4*)(ptile4 + p * 4) = q;
    }
    // ---- stage t8: 8ch conv tile, halo 1, stride 33 ----
    for (int i = tid; i < 8 * 18 * 18; i += 256) {
        const int c   = i / 324;
        const int rem = i - c * 324;
        const int row = rem / 18;
        const int col = rem - row * 18;
        const int gy = tileY0 + row - 1, gx = tileX0 + col - 1;
        const float* plane;
        if (c < 3)      plane = pf + ((size_t)b * 3 + c) * HWn;
        else if (c < 6) plane = cf + ((size_t)b * 3 + (c - 3)) * HWn;
        else            plane = mv + ((size_t)b * 2 + (c - 6)) * HWn;
        const bool v = ((unsigned)gy < (unsigned)Hn) && ((unsigned)gx < (unsigned)Wn);
        t8[c * CPL + row * CSTR + col] = v ? plane[gy * Wn + gx] : 0.f;
    }
    __syncthreads();

    // ---- MFMA GEMM [256 x 128] @ [128 x 32] ----
    f32x4 acc[4][2];
#pragma unroll
    for (int mt = 0; mt < 4; ++mt)
#pragma unroll
        for (int nt = 0; nt < 2; ++nt)
            acc[mt][nt] = (f32x4){0.f, 0.f, 0.f, 0.f};

#pragma unroll
    for (int mt = 0; mt < 4; ++mt) {
        const int mrow = wv * 4 + mt;            // pixel ty
#pragma unroll
        for (int s = 0; s < 4; ++s) {
            const int c = 2 * s + chalf;
            const float* ap = t8 + c * CPL + mrow * CSTR + am;
            union { unsigned u[4]; s16x8 v; } A;
            if (!hiK) {
                const float t0 = ap[0],        t1 = ap[1],        t2 = ap[2];
                const float t3 = ap[CSTR],     t4 = ap[CSTR + 1], t5 = ap[CSTR + 2];
                const float t6 = ap[2*CSTR],   t7 = ap[2*CSTR+1];
                A.u[0] = pack_bf16(t0, t1);
                A.u[1] = pack_bf16(t2, t3);
                A.u[2] = pack_bf16(t4, t5);
                A.u[3] = pack_bf16(t6, t7);
            } else {
                const float t8v = ap[2*CSTR+2];
                A.u[0] = __float_as_uint(t8v) >> 16;
                A.u[1] = 0u; A.u[2] = 0u; A.u[3] = 0u;
            }
            acc[mt][0] = __builtin_amdgcn_mfma_f32_16x16x32_bf16(A.v, bfrag[s][0], acc[mt][0], 0, 0, 0);
            acc[mt][1] = __builtin_amdgcn_mfma_f32_16x16x32_bf16(A.v, bfrag[s][1], acc[mt][1], 0, 0, 0);
        }
    }
    __syncthreads();   // t8 reads done; region becomes offb

    // ---- redistribute D -> offb[pixel][oc], stride 19 ----
    float* offb = smem + OFF_T8;
#pragma unroll
    for (int mt = 0; mt < 4; ++mt) {
        const int prow = wv * 4 + mt;
#pragma unroll
        for (int r = 0; r < 4; ++r) {
            const int pix = prow * 16 + (g * 4 + r);
            offb[pix * 19 + am] = acc[mt][0][r];
            if (am < 2) offb[pix * 19 + 16 + am] = acc[mt][1][r];
        }
    }
    __syncthreads();

    // ---- per-pixel offsets + stage-2 deformable conv ----
    const int tx = tid & 15;
    const int ty = tid >> 4;
    const int x = tileX0 + tx;
    const int y = tileY0 + ty;

    float offs[18];
#pragma unroll
    for (int j = 0; j < 18; ++j) offs[j] = offb[tid * 19 + j] + ob[j];

    const float* p0 = pf + (size_t)b * 3 * HWn;
    float acc2[3] = {0.f, 0.f, 0.f};

#pragma unroll
    for (int k = 0; k < 9; ++k) {
        const int ky = k / 3;
        const int kx = k - ky * 3;
        const float py = offs[2 * k]     + (float)(y + ky - 1);
        const float px = offs[2 * k + 1] + (float)(x + kx - 1);
        const float y0f = floorf(py);
        const float x0f = floorf(px);
        const float wy = py - y0f;
        const float wx = px - x0f;
        const int y0 = (int)y0f, x0 = (int)x0f;
        const int y1 = y0 + 1,  x1 = x0 + 1;
        const bool vy0 = ((unsigned)y0 < (unsigned)Hn);
        const bool vy1 = ((unsigned)y1 < (unsigned)Hn);
        const bool vx0 = ((unsigned)x0 < (unsigned)Wn);
        const bool vx1 = ((unsigned)x1 < (unsigned)Wn);
        const int y0c = min(max(y0, 0), Hn - 1);
        const int y1c = min(max(y1, 0), Hn - 1);
        const int x0c = min(max(x0, 0), Wn - 1);
        const int x1c = min(max(x1, 0), Wn - 1);
        const float w00 = (1.f - wy) * (1.f - wx);
        const float w01 = (1.f - wy) * wx;
        const float w10 = wy * (1.f - wx);
        const float w11 = wy * wx;

        const int ty0 = y0c - oy, tx0 = x0c - ox;
        const int ty1 = y1c - oy, tx1 = x1c - ox;
        const bool inT = ((unsigned)ty0 < (unsigned)PT) && ((unsigned)ty1 < (unsigned)PT) &&
                         ((unsigned)tx0 < (unsigned)PT) && ((unsigned)tx1 < (unsigned)PT);

        if (inT) {
            const float m00 = (vy0 && vx0) ? w00 : 0.f;
            const float m01 = (vy0 && vx1) ? w01 : 0.f;
            const float m10 = (vy1 && vx0) ? w10 : 0.f;
            const float m11 = (vy1 && vx1) ? w11 : 0.f;
            const f32x4 q00 = *(const f32x4*)(ptile4 + (ty0 * PT + tx0) * 4);
            const f32x4 q01 = *(const f32x4*)(ptile4 + (ty0 * PT + tx1) * 4);
            const f32x4 q10 = *(const f32x4*)(ptile4 + (ty1 * PT + tx0) * 4);
            const f32x4 q11 = *(const f32x4*)(ptile4 + (ty1 * PT + tx1) * 4);
#pragma unroll
            for (int i = 0; i < 3; ++i) {
                const float s = m00 * q00[i] + m01 * q01[i] + m10 * q10[i] + m11 * q11[i];
#pragma unroll
                for (int o = 0; o < 3; ++o)
                    acc2[o] = fmaf(dw[o * 27 + i * 9 + k], s, acc2[o]);
            }
        } else {
            const int i00 = y0c * Wn + x0c;
            const int i01 = y0c * Wn + x1c;
            const int i10 = y1c * Wn + x0c;
            const int i11 = y1c * Wn + x1c;
#pragma unroll
            for (int i = 0; i < 3; ++i) {
                const float* pl = p0 + (size_t)i * HWn;
                const float v00 = (vy0 && vx0) ? pl[i00] : 0.f;
                const float v01 = (vy0 && vx1) ? pl[i01] : 0.f;
                const float v10 = (vy1 && vx0) ? pl[i10] : 0.f;
                const float v11 = (vy1 && vx1) ? pl[i11] : 0.f;
                const float s = w00 * v00 + w01 * v01 + w10 * v10 + w11 * v11;
#pragma unroll
                for (int o = 0; o < 3; ++o)
                    acc2[o] = fmaf(dw[o * 27 + i * 9 + k], s, acc2[o]);
            }
        }
    }

#pragma unroll
    for (int o = 0; o < 3; ++o) {
        out[(((size_t)b * 3 + o) * Hn + y) * Wn + x] = acc2[o];
    }
}

extern "C" void kernel_launch(void* const* d_in, const int* in_sizes, int n_in,
                              void* d_out, int out_size, void* d_ws, size_t ws_size,
                              hipStream_t stream) {
    const float* pf = (const float*)d_in[0];
    const float* cf = (const float*)d_in[1];
    const float* mv = (const float*)d_in[2];
    const float* ow = (const float*)d_in[3];
    const float* ob = (const float*)d_in[4];
    const float* dw = (const float*)d_in[5];
    float* out = (float*)d_out;

    dim3 grid(Wn / TILE, Hn / TILE, Bn);   // 24 x 24 x 8
    guided_cnn_fused<<<grid, 256, 0, stream>>>(pf, cf, mv, ow, ob, dw, out);
}

// Round 7
// 137.730 us; speedup vs baseline: 1.3668x; 1.3668x over previous
//
#include <hip/hip_runtime.h>

// GuidedCnn: fused offset-conv (8ch -> 18ch, 3x3) + deformable conv.
// R7: (1) prep kernel precomputes bf16 MFMA B-fragments into d_ws ->
// main kernel loads B with 6 coalesced dwordx4 (R6's 64 scattered global
// loads/lane were the regression). (2) K repacked as k=tap*8+ch: K=96,
// 3 k-steps (was 4), A-fragment = 8 channels at one position = 2x
// ds_read_b128 from channel-interleaved conv tile [row][col][12].

#define Bn 8
#define Hn 384
#define Wn 384
#define HWn (Hn * Wn)
#define TILE 16
#define PH 8
#define PT 32                  // pf sampling tile extent (halo 8)
#define TRS 216                // t8i row stride (18 cols * 12)
#define TCS 12                 // t8i col stride (floats; 48B, b128-aligned)

// LDS float-offset map
#define OFF_PTILE 0
#define SZ_PTILE (PT * PT * 4)           // 4096 floats, [pix][ch0..2,pad]
#define OFF_T8   SZ_PTILE
#define SZ_T8U   4864                    // max(t8i 18*216=3888, offb 256*19=4864)
#define SMEM_FLOATS (OFF_T8 + SZ_T8U)    // 8960 floats = 35,840 B

typedef float f32x4 __attribute__((ext_vector_type(4)));
typedef short s16x8 __attribute__((ext_vector_type(8)));

__device__ inline unsigned pack_bf16(float lo, float hi) {
    return (__float_as_uint(hi) & 0xffff0000u) | (__float_as_uint(lo) >> 16);
}
__device__ inline unsigned short rne_bf16(float f) {
    unsigned u = __float_as_uint(f);
    u += 0x7fffu + ((u >> 16) & 1u);
    return (unsigned short)(u >> 16);
}

// ---- prep: B-fragments, layout [sg = s*2+nt][lane][j=ch], k = tap*8+ch ----
__global__ void prep_bw(const float* __restrict__ ow, unsigned short* __restrict__ bwg) {
    const int idx = blockIdx.x * 64 + threadIdx.x;   // 0..383
    const int sg   = idx >> 6;
    const int lane = idx & 63;
    const int s  = sg >> 1;
    const int nt = sg & 1;
    const int am = lane & 15;
    const int g  = lane >> 4;
    const int oc = nt * 16 + am;
    const int t  = 4 * s + g;                        // tap 0..11
    union { unsigned short h[8]; s16x8 v; } F;
#pragma unroll
    for (int c = 0; c < 8; ++c) {
        float w = 0.f;
        if (t < 9 && oc < 18) w = ow[oc * 72 + c * 9 + t];
        F.h[c] = rne_bf16(w);
    }
    ((s16x8*)bwg)[idx] = F.v;
}

__global__ __launch_bounds__(256, 4) void guided_cnn_fused(
    const float* __restrict__ pf, const float* __restrict__ cf,
    const float* __restrict__ mv, const s16x8* __restrict__ bwg,
    const float* __restrict__ ob, const float* __restrict__ dw,
    float* __restrict__ out)
{
    __shared__ float smem[SMEM_FLOATS];

    const int tid = threadIdx.x;
    const int b = blockIdx.z;
    const int tileY0 = blockIdx.y * TILE;
    const int tileX0 = blockIdx.x * TILE;
    const int oy = tileY0 - PH;
    const int ox = tileX0 - PH;

    float* ptile4 = smem + OFF_PTILE;
    float* t8i    = smem + OFF_T8;

    const int lane = tid & 63;
    const int wv   = tid >> 6;
    const int am   = lane & 15;
    const int g    = lane >> 4;

    // ---- B-fragments: 6 coalesced b128 loads from precomputed d_ws ----
    s16x8 bfrag[3][2];
#pragma unroll
    for (int s = 0; s < 3; ++s)
#pragma unroll
        for (int nt = 0; nt < 2; ++nt)
            bfrag[s][nt] = bwg[(s * 2 + nt) * 64 + lane];

    // ---- stage ptile4: pf 3ch interleaved [pix][4], b128 writes ----
    for (int p = tid; p < PT * PT; p += 256) {
        const int row = p >> 5;
        const int col = p & 31;
        const int gy = oy + row, gx = ox + col;
        const bool v = ((unsigned)gy < (unsigned)Hn) && ((unsigned)gx < (unsigned)Wn);
        const size_t gidx = (size_t)b * 3 * HWn + gy * Wn + gx;
        f32x4 q;
        q[0] = v ? pf[gidx] : 0.f;
        q[1] = v ? pf[gidx + HWn] : 0.f;
        q[2] = v ? pf[gidx + 2 * HWn] : 0.f;
        q[3] = 0.f;
        *(f32x4*)(ptile4 + p * 4) = q;
    }
    // ---- stage t8i: 8ch conv tile (halo 1), channel-interleaved ----
    for (int i = tid; i < 8 * 324; i += 256) {
        const int c   = i / 324;
        const int rem = i - c * 324;
        const int row = rem / 18;
        const int col = rem - row * 18;
        const int gy = tileY0 + row - 1, gx = tileX0 + col - 1;
        const float* plane;
        if (c < 3)      plane = pf + ((size_t)b * 3 + c) * HWn;
        else if (c < 6) plane = cf + ((size_t)b * 3 + (c - 3)) * HWn;
        else            plane = mv + ((size_t)b * 2 + (c - 6)) * HWn;
        const bool v = ((unsigned)gy < (unsigned)Hn) && ((unsigned)gx < (unsigned)Wn);
        t8i[row * TRS + col * TCS + c] = v ? plane[gy * Wn + gx] : 0.f;
    }
    __syncthreads();

    // ---- MFMA GEMM [256 x 96] @ [96 x 32] ----
    f32x4 acc[4][2];
#pragma unroll
    for (int mt = 0; mt < 4; ++mt)
#pragma unroll
        for (int nt = 0; nt < 2; ++nt)
            acc[mt][nt] = (f32x4){0.f, 0.f, 0.f, 0.f};

    const int t_of_g[3] = {0 + g, 4 + g, 8 + g};   // lane's tap per k-step
#pragma unroll
    for (int mt = 0; mt < 4; ++mt) {
        const int mrow = wv * 4 + mt;              // pixel row (ty)
#pragma unroll
        for (int s = 0; s < 3; ++s) {
            const int t  = t_of_g[s];
            const bool tv = (t < 9);
            const int tc = tv ? t : 0;
            const int dy = tc / 3, dx = tc - dy * 3;
            const float* base = t8i + (mrow + dy) * TRS + (am + dx) * TCS;
            const f32x4 lo = *(const f32x4*)base;
            const f32x4 hi = *(const f32x4*)(base + 4);
            union { unsigned u[4]; s16x8 v; } A;
            A.u[0] = tv ? pack_bf16(lo[0], lo[1]) : 0u;
            A.u[1] = tv ? pack_bf16(lo[2], lo[3]) : 0u;
            A.u[2] = tv ? pack_bf16(hi[0], hi[1]) : 0u;
            A.u[3] = tv ? pack_bf16(hi[2], hi[3]) : 0u;
            acc[mt][0] = __builtin_amdgcn_mfma_f32_16x16x32_bf16(A.v, bfrag[s][0], acc[mt][0], 0, 0, 0);
            acc[mt][1] = __builtin_amdgcn_mfma_f32_16x16x32_bf16(A.v, bfrag[s][1], acc[mt][1], 0, 0, 0);
        }
    }
    __syncthreads();   // t8i reads done; region becomes offb

    // ---- redistribute D -> offb[pixel][oc], stride 19 ----
    float* offb = smem + OFF_T8;
#pragma unroll
    for (int mt = 0; mt < 4; ++mt) {
        const int prow = wv * 4 + mt;
#pragma unroll
        for (int r = 0; r < 4; ++r) {
            const int pix = prow * 16 + (g * 4 + r);
            offb[pix * 19 + am] = acc[mt][0][r];
            if (am < 2) offb[pix * 19 + 16 + am] = acc[mt][1][r];
        }
    }
    __syncthreads();

    // ---- per-pixel offsets + stage-2 deformable conv ----
    const int tx = tid & 15;
    const int ty = tid >> 4;
    const int x = tileX0 + tx;
    const int y = tileY0 + ty;

    float offs[18];
#pragma unroll
    for (int j = 0; j < 18; ++j) offs[j] = offb[tid * 19 + j] + ob[j];

    const float* p0 = pf + (size_t)b * 3 * HWn;
    float acc2[3] = {0.f, 0.f, 0.f};

#pragma unroll
    for (int k = 0; k < 9; ++k) {
        const int ky = k / 3;
        const int kx = k - ky * 3;
        const float py = offs[2 * k]     + (float)(y + ky - 1);
        const float px = offs[2 * k + 1] + (float)(x + kx - 1);
        const float y0f = floorf(py);
        const float x0f = floorf(px);
        const float wy = py - y0f;
        const float wx = px - x0f;
        const int y0 = (int)y0f, x0 = (int)x0f;
        const int y1 = y0 + 1,  x1 = x0 + 1;
        const bool vy0 = ((unsigned)y0 < (unsigned)Hn);
        const bool vy1 = ((unsigned)y1 < (unsigned)Hn);
        const bool vx0 = ((unsigned)x0 < (unsigned)Wn);
        const bool vx1 = ((unsigned)x1 < (unsigned)Wn);
        const int y0c = min(max(y0, 0), Hn - 1);
        const int y1c = min(max(y1, 0), Hn - 1);
        const int x0c = min(max(x0, 0), Wn - 1);
        const int x1c = min(max(x1, 0), Wn - 1);
        const float w00 = (1.f - wy) * (1.f - wx);
        const float w01 = (1.f - wy) * wx;
        const float w10 = wy * (1.f - wx);
        const float w11 = wy * wx;

        const int ty0 = y0c - oy, tx0 = x0c - ox;
        const int ty1 = y1c - oy, tx1 = x1c - ox;
        const bool inT = ((unsigned)ty0 < (unsigned)PT) && ((unsigned)ty1 < (unsigned)PT) &&
                         ((unsigned)tx0 < (unsigned)PT) && ((unsigned)tx1 < (unsigned)PT);

        if (inT) {
            const float m00 = (vy0 && vx0) ? w00 : 0.f;
            const float m01 = (vy0 && vx1) ? w01 : 0.f;
            const float m10 = (vy1 && vx0) ? w10 : 0.f;
            const float m11 = (vy1 && vx1) ? w11 : 0.f;
            const f32x4 q00 = *(const f32x4*)(ptile4 + (ty0 * PT + tx0) * 4);
            const f32x4 q01 = *(const f32x4*)(ptile4 + (ty0 * PT + tx1) * 4);
            const f32x4 q10 = *(const f32x4*)(ptile4 + (ty1 * PT + tx0) * 4);
            const f32x4 q11 = *(const f32x4*)(ptile4 + (ty1 * PT + tx1) * 4);
#pragma unroll
            for (int i = 0; i < 3; ++i) {
                const float s = m00 * q00[i] + m01 * q01[i] + m10 * q10[i] + m11 * q11[i];
#pragma unroll
                for (int o = 0; o < 3; ++o)
                    acc2[o] = fmaf(dw[o * 27 + i * 9 + k], s, acc2[o]);
            }
        } else {
            const int i00 = y0c * Wn + x0c;
            const int i01 = y0c * Wn + x1c;
            const int i10 = y1c * Wn + x0c;
            const int i11 = y1c * Wn + x1c;
#pragma unroll
            for (int i = 0; i < 3; ++i) {
                const float* pl = p0 + (size_t)i * HWn;
                const float v00 = (vy0 && vx0) ? pl[i00] : 0.f;
                const float v01 = (vy0 && vx1) ? pl[i01] : 0.f;
                const float v10 = (vy1 && vx0) ? pl[i10] : 0.f;
                const float v11 = (vy1 && vx1) ? pl[i11] : 0.f;
                const float s = w00 * v00 + w01 * v01 + w10 * v10 + w11 * v11;
#pragma unroll
                for (int o = 0; o < 3; ++o)
                    acc2[o] = fmaf(dw[o * 27 + i * 9 + k], s, acc2[o]);
            }
        }
    }

#pragma unroll
    for (int o = 0; o < 3; ++o) {
        out[(((size_t)b * 3 + o) * Hn + y) * Wn + x] = acc2[o];
    }
}

extern "C" void kernel_launch(void* const* d_in, const int* in_sizes, int n_in,
                              void* d_out, int out_size, void* d_ws, size_t ws_size,
                              hipStream_t stream) {
    const float* pf = (const float*)d_in[0];
    const float* cf = (const float*)d_in[1];
    const float* mv = (const float*)d_in[2];
    const float* ow = (const float*)d_in[3];
    const float* ob = (const float*)d_in[4];
    const float* dw = (const float*)d_in[5];
    float* out = (float*)d_out;
    unsigned short* bwg = (unsigned short*)d_ws;   // 6*64*8 ushorts = 6 KB

    prep_bw<<<6, 64, 0, stream>>>(ow, bwg);
    dim3 grid(Wn / TILE, Hn / TILE, Bn);   // 24 x 24 x 8
    guided_cnn_fused<<<grid, 256, 0, stream>>>(pf, cf, mv, (const s16x8*)bwg, ob, dw, out);
}

// Round 8
// 118.615 us; speedup vs baseline: 1.5871x; 1.1611x over previous
//
#include <hip/hip_runtime.h>

// GuidedCnn: fused offset-conv (8ch -> 18ch, 3x3) + deformable conv.
// R8: VALU diet. (1) conv tile pre-converted to bf16 at staging: A-frag =
// one ds_read_b128, no repacking. (2) stage-2 in-tile path drops ALL
// validity masks/clamps -- the zero-filled LDS tile already reproduces
// `valid*value` semantics; masks live only in the (rare) global fallback.
// (3) tile-relative sample coords; corners via immediate LDS offsets.
// (4) PH=6 -> 32.0 KB LDS -> 5 blocks/CU.

#define Bn 8
#define Hn 384
#define Wn 384
#define HWn (Hn * Wn)
#define TILE 16
#define PH 6
#define PT 28                  // pf sampling tile extent (halo 6)

// LDS float-offset map
#define OFF_PTILE 0
#define SZ_PTILE (PT * PT * 4)           // 3136 floats, [pix][ch0..2,pad]
#define OFF_T8   SZ_PTILE
#define SZ_T8U   4864                    // max(t8 bf16 18*18*4=1296, offb 256*19)
#define SMEM_FLOATS (OFF_T8 + SZ_T8U)    // 8000 floats = 32,000 B

typedef float f32x4 __attribute__((ext_vector_type(4)));
typedef short s16x8 __attribute__((ext_vector_type(8)));

__device__ inline unsigned short rne_bf16(float f) {
    unsigned u = __float_as_uint(f);
    u += 0x7fffu + ((u >> 16) & 1u);
    return (unsigned short)(u >> 16);
}

// ---- prep: B-fragments, layout [sg = s*2+nt][lane][j=ch], k = tap*8+ch ----
__global__ void prep_bw(const float* __restrict__ ow, unsigned short* __restrict__ bwg) {
    const int idx = blockIdx.x * 64 + threadIdx.x;   // 0..383
    const int sg   = idx >> 6;
    const int lane = idx & 63;
    const int s  = sg >> 1;
    const int nt = sg & 1;
    const int am = lane & 15;
    const int g  = lane >> 4;
    const int oc = nt * 16 + am;
    const int t  = 4 * s + g;                        // tap 0..11
    union { unsigned short h[8]; s16x8 v; } F;
#pragma unroll
    for (int c = 0; c < 8; ++c) {
        float w = 0.f;
        if (t < 9 && oc < 18) w = ow[oc * 72 + c * 9 + t];
        F.h[c] = rne_bf16(w);
    }
    ((s16x8*)bwg)[idx] = F.v;
}

__global__ __launch_bounds__(256, 5) void guided_cnn_fused(
    const float* __restrict__ pf, const float* __restrict__ cf,
    const float* __restrict__ mv, const s16x8* __restrict__ bwg,
    const float* __restrict__ ob, const float* __restrict__ dw,
    float* __restrict__ out)
{
    __shared__ float smem[SMEM_FLOATS];

    const int tid = threadIdx.x;
    const int b = blockIdx.z;
    const int tileY0 = blockIdx.y * TILE;
    const int tileX0 = blockIdx.x * TILE;
    const int oy = tileY0 - PH;
    const int ox = tileX0 - PH;

    float* ptile4 = smem + OFF_PTILE;
    float* t8b    = smem + OFF_T8;       // bf16 conv tile: [pix][8ch] = 16B

    const int lane = tid & 63;
    const int wv   = tid >> 6;
    const int am   = lane & 15;
    const int g    = lane >> 4;

    // ---- B-fragments: 6 coalesced b128 loads from precomputed d_ws ----
    s16x8 bfrag[3][2];
#pragma unroll
    for (int s = 0; s < 3; ++s)
#pragma unroll
        for (int nt = 0; nt < 2; ++nt)
            bfrag[s][nt] = bwg[(s * 2 + nt) * 64 + lane];

    // ---- stage ptile4: pf 3ch interleaved [pix][4] (zero-filled OOB) ----
    for (int p = tid; p < PT * PT; p += 256) {
        const int row = p / PT;
        const int col = p - row * PT;
        const int gy = oy + row, gx = ox + col;
        const bool v = ((unsigned)gy < (unsigned)Hn) && ((unsigned)gx < (unsigned)Wn);
        const size_t gidx = (size_t)b * 3 * HWn + gy * Wn + gx;
        f32x4 q;
        q[0] = v ? pf[gidx] : 0.f;
        q[1] = v ? pf[gidx + HWn] : 0.f;
        q[2] = v ? pf[gidx + 2 * HWn] : 0.f;
        q[3] = 0.f;
        *(f32x4*)(ptile4 + p * 4) = q;
    }
    // ---- stage t8b: 8ch conv tile (halo 1), bf16-packed [pix][8ch] ----
    for (int p = tid; p < 324; p += 256) {
        const int row = p / 18;
        const int col = p - row * 18;
        const int gy = tileY0 + row - 1, gx = tileX0 + col - 1;
        const bool v = ((unsigned)gy < (unsigned)Hn) && ((unsigned)gx < (unsigned)Wn);
        const size_t base = (size_t)b * 3 * HWn + gy * Wn + gx;
        float c0 = v ? pf[base] : 0.f;
        float c1 = v ? pf[base + HWn] : 0.f;
        float c2 = v ? pf[base + 2 * HWn] : 0.f;
        float c3 = v ? cf[base] : 0.f;
        float c4 = v ? cf[base + HWn] : 0.f;
        float c5 = v ? cf[base + 2 * HWn] : 0.f;
        const size_t mbase = (size_t)b * 2 * HWn + gy * Wn + gx;
        float c6 = v ? mv[mbase] : 0.f;
        float c7 = v ? mv[mbase + HWn] : 0.f;
        union { unsigned u[4]; f32x4 f; } P;
        P.u[0] = (unsigned)rne_bf16(c0) | ((unsigned)rne_bf16(c1) << 16);
        P.u[1] = (unsigned)rne_bf16(c2) | ((unsigned)rne_bf16(c3) << 16);
        P.u[2] = (unsigned)rne_bf16(c4) | ((unsigned)rne_bf16(c5) << 16);
        P.u[3] = (unsigned)rne_bf16(c6) | ((unsigned)rne_bf16(c7) << 16);
        *(f32x4*)(t8b + p * 4) = P.f;
    }
    __syncthreads();

    // ---- MFMA GEMM [256 x 96] @ [96 x 32] ----
    f32x4 acc[4][2];
#pragma unroll
    for (int mt = 0; mt < 4; ++mt)
#pragma unroll
        for (int nt = 0; nt < 2; ++nt)
            acc[mt][nt] = (f32x4){0.f, 0.f, 0.f, 0.f};

#pragma unroll
    for (int mt = 0; mt < 4; ++mt) {
        const int mrow = wv * 4 + mt;              // pixel row (ty)
#pragma unroll
        for (int s = 0; s < 3; ++s) {
            const int tap = 4 * s + g;             // this lane's tap
            const int tc  = tap < 9 ? tap : 8;     // pad taps: B=0, any A ok
            const int dy = tc / 3, dx = tc - dy * 3;
            union { f32x4 f; s16x8 v; } A;
            A.f = *(const f32x4*)(t8b + ((mrow + dy) * 18 + (am + dx)) * 4);
            acc[mt][0] = __builtin_amdgcn_mfma_f32_16x16x32_bf16(A.v, bfrag[s][0], acc[mt][0], 0, 0, 0);
            acc[mt][1] = __builtin_amdgcn_mfma_f32_16x16x32_bf16(A.v, bfrag[s][1], acc[mt][1], 0, 0, 0);
        }
    }
    __syncthreads();   // t8b reads done; region becomes offb

    // ---- redistribute D -> offb[pixel][oc], stride 19 ----
    float* offb = smem + OFF_T8;
#pragma unroll
    for (int mt = 0; mt < 4; ++mt) {
        const int prow = wv * 4 + mt;
#pragma unroll
        for (int r = 0; r < 4; ++r) {
            const int pix = prow * 16 + (g * 4 + r);
            offb[pix * 19 + am] = acc[mt][0][r];
            if (am < 2) offb[pix * 19 + 16 + am] = acc[mt][1][r];
        }
    }
    __syncthreads();

    // ---- per-pixel offsets + stage-2 deformable conv ----
    const int tx = tid & 15;
    const int ty = tid >> 4;
    const int x = tileX0 + tx;
    const int y = tileY0 + ty;

    float offs[18];
#pragma unroll
    for (int j = 0; j < 18; ++j) offs[j] = offb[tid * 19 + j] + ob[j];

    const float* p0 = pf + (size_t)b * 3 * HWn;
    float acc2[3] = {0.f, 0.f, 0.f};

#pragma unroll
    for (int k = 0; k < 9; ++k) {
        const int ky = k / 3;
        const int kx = k - ky * 3;
        // tile-relative sample coords (tile origin = pixel - PH)
        const float rpy = offs[2 * k]     + (float)(ty + ky - 1 + PH);
        const float rpx = offs[2 * k + 1] + (float)(tx + kx - 1 + PH);
        const float y0f = floorf(rpy);
        const float x0f = floorf(rpx);
        const float wy = rpy - y0f;
        const float wx = rpx - x0f;
        const int ty0 = (int)y0f;
        const int tx0 = (int)x0f;
        const float w00 = (1.f - wy) * (1.f - wx);
        const float w01 = (1.f - wy) * wx;
        const float w10 = wy * (1.f - wx);
        const float w11 = wy * wx;

        const bool inT = ((unsigned)ty0 < (unsigned)(PT - 1)) &&
                         ((unsigned)tx0 < (unsigned)(PT - 1));
        if (inT) {
            // zero-filled tile == valid*value semantics; no masks needed
            const float* base = ptile4 + (ty0 * PT + tx0) * 4;
            const f32x4 q00 = *(const f32x4*)(base);
            const f32x4 q01 = *(const f32x4*)(base + 4);
            const f32x4 q10 = *(const f32x4*)(base + 4 * PT);
            const f32x4 q11 = *(const f32x4*)(base + 4 * PT + 4);
#pragma unroll
            for (int i = 0; i < 3; ++i) {
                const float s = w00 * q00[i] + w01 * q01[i] + w10 * q10[i] + w11 * q11[i];
#pragma unroll
                for (int o = 0; o < 3; ++o)
                    acc2[o] = fmaf(dw[o * 27 + i * 9 + k], s, acc2[o]);
            }
        } else {
            const int y0 = ty0 + oy, x0 = tx0 + ox;
            const int y1 = y0 + 1,  x1 = x0 + 1;
            const bool vy0 = ((unsigned)y0 < (unsigned)Hn);
            const bool vy1 = ((unsigned)y1 < (unsigned)Hn);
            const bool vx0 = ((unsigned)x0 < (unsigned)Wn);
            const bool vx1 = ((unsigned)x1 < (unsigned)Wn);
            const int y0c = min(max(y0, 0), Hn - 1);
            const int y1c = min(max(y1, 0), Hn - 1);
            const int x0c = min(max(x0, 0), Wn - 1);
            const int x1c = min(max(x1, 0), Wn - 1);
            const int i00 = y0c * Wn + x0c;
            const int i01 = y0c * Wn + x1c;
            const int i10 = y1c * Wn + x0c;
            const int i11 = y1c * Wn + x1c;
#pragma unroll
            for (int i = 0; i < 3; ++i) {
                const float* pl = p0 + (size_t)i * HWn;
                const float v00 = (vy0 && vx0) ? pl[i00] : 0.f;
                const float v01 = (vy0 && vx1) ? pl[i01] : 0.f;
                const float v10 = (vy1 && vx0) ? pl[i10] : 0.f;
                const float v11 = (vy1 && vx1) ? pl[i11] : 0.f;
                const float s = w00 * v00 + w01 * v01 + w10 * v10 + w11 * v11;
#pragma unroll
                for (int o = 0; o < 3; ++o)
                    acc2[o] = fmaf(dw[o * 27 + i * 9 + k], s, acc2[o]);
            }
        }
    }

#pragma unroll
    for (int o = 0; o < 3; ++o) {
        out[(((size_t)b * 3 + o) * Hn + y) * Wn + x] = acc2[o];
    }
}

extern "C" void kernel_launch(void* const* d_in, const int* in_sizes, int n_in,
                              void* d_out, int out_size, void* d_ws, size_t ws_size,
                              hipStream_t stream) {
    const float* pf = (const float*)d_in[0];
    const float* cf = (const float*)d_in[1];
    const float* mv = (const float*)d_in[2];
    const float* ow = (const float*)d_in[3];
    const float* ob = (const float*)d_in[4];
    const float* dw = (const float*)d_in[5];
    float* out = (float*)d_out;
    unsigned short* bwg = (unsigned short*)d_ws;   // 6*64*8 ushorts = 6 KB

    prep_bw<<<6, 64, 0, stream>>>(ow, bwg);
    dim3 grid(Wn / TILE, Hn / TILE, Bn);   // 24 x 24 x 8
    guided_cnn_fused<<<grid, 256, 0, stream>>>(pf, cf, mv, (const s16x8*)bwg, ob, dw, out);
}

// Round 10
// 115.720 us; speedup vs baseline: 1.6268x; 1.0250x over previous
//
#include <hip/hip_runtime.h>

// GuidedCnn: fused offset-conv (8ch -> 18ch, 3x3) + deformable conv.
// R9b: (1) stage-2 bilinear in lerp form, channel-pairs packed in f32x2 via
// __builtin_elementwise_fma -> v_pk_fma_f32 (dual-issue FP32); epilogue
// packed over output pairs. (2) bias folded into MFMA C-operand init.
// (3) LDS 26.4 KB (ptile 12B/px, PH=4, PT=24) -> 6 blocks/CU.
// (R9 fix: VFMA/VFLOOR as inline functions, not macros — compound-literal
// commas broke macro argument parsing.)

#define Bn 8
#define Hn 384
#define Wn 384
#define HWn (Hn * Wn)
#define TILE 16
#define PH 4
#define PT 24                  // pf sampling tile extent (halo 4)

// LDS float-offset map
#define OFF_PTILE 0
#define SZ_PTILE (PT * PT * 3)           // 1728 floats, [pix][ch0..2]
#define OFF_T8   SZ_PTILE
#define SZ_T8U   4864                    // max(t8b 324*4=1296, offb 256*19=4864)
#define SMEM_FLOATS (OFF_T8 + SZ_T8U)    // 6592 floats = 26,368 B

typedef float f32x4 __attribute__((ext_vector_type(4)));
typedef float f32x2 __attribute__((ext_vector_type(2)));
typedef short s16x8 __attribute__((ext_vector_type(8)));

static __device__ inline f32x2 vfma2(f32x2 a, f32x2 b, f32x2 c) {
#if __has_builtin(__builtin_elementwise_fma)
    return __builtin_elementwise_fma(a, b, c);
#else
    f32x2 r; r.x = fmaf(a.x, b.x, c.x); r.y = fmaf(a.y, b.y, c.y); return r;
#endif
}
static __device__ inline f32x2 vfloor2(f32x2 a) {
#if __has_builtin(__builtin_elementwise_floor)
    return __builtin_elementwise_floor(a);
#else
    f32x2 r; r.x = floorf(a.x); r.y = floorf(a.y); return r;
#endif
}
static __device__ inline f32x2 splat2(float s) {
    f32x2 r; r.x = s; r.y = s; return r;
}

__device__ inline unsigned short rne_bf16(float f) {
    unsigned u = __float_as_uint(f);
    u += 0x7fffu + ((u >> 16) & 1u);
    return (unsigned short)(u >> 16);
}

// ---- prep: B-fragments, layout [sg = s*2+nt][lane][j=ch], k = tap*8+ch ----
__global__ void prep_bw(const float* __restrict__ ow, unsigned short* __restrict__ bwg) {
    const int idx = blockIdx.x * 64 + threadIdx.x;   // 0..383
    const int sg   = idx >> 6;
    const int lane = idx & 63;
    const int s  = sg >> 1;
    const int nt = sg & 1;
    const int am = lane & 15;
    const int g  = lane >> 4;
    const int oc = nt * 16 + am;
    const int t  = 4 * s + g;                        // tap 0..11
    union { unsigned short h[8]; s16x8 v; } F;
#pragma unroll
    for (int c = 0; c < 8; ++c) {
        float w = 0.f;
        if (t < 9 && oc < 18) w = ow[oc * 72 + c * 9 + t];
        F.h[c] = rne_bf16(w);
    }
    ((s16x8*)bwg)[idx] = F.v;
}

__global__ __launch_bounds__(256, 6) void guided_cnn_fused(
    const float* __restrict__ pf, const float* __restrict__ cf,
    const float* __restrict__ mv, const s16x8* __restrict__ bwg,
    const float* __restrict__ ob, const float* __restrict__ dw,
    float* __restrict__ out)
{
    __shared__ float smem[SMEM_FLOATS];

    const int tid = threadIdx.x;
    const int b = blockIdx.z;
    const int tileY0 = blockIdx.y * TILE;
    const int tileX0 = blockIdx.x * TILE;
    const int oy = tileY0 - PH;
    const int ox = tileX0 - PH;

    float* ptile3 = smem + OFF_PTILE;    // [pix][3ch], 12 B/pixel
    float* t8b    = smem + OFF_T8;       // bf16 conv tile: [pix][8ch] = 16B

    const int lane = tid & 63;
    const int wv   = tid >> 6;
    const int am   = lane & 15;
    const int g    = lane >> 4;

    // ---- B-fragments: 6 coalesced b128 loads from precomputed d_ws ----
    s16x8 bfrag[3][2];
#pragma unroll
    for (int s = 0; s < 3; ++s)
#pragma unroll
        for (int nt = 0; nt < 2; ++nt)
            bfrag[s][nt] = bwg[(s * 2 + nt) * 64 + lane];

    // bias for this lane's D-columns (C-operand init)
    const float bias0 = ob[am];
    const float bias1 = ob[am < 2 ? 16 + am : 17];   // cols >=18 discarded

    // ---- stage ptile3: pf 3ch, 12B/pixel (zero-filled OOB) ----
    for (int p = tid; p < PT * PT; p += 256) {
        const int row = p / PT;
        const int col = p - row * PT;
        const int gy = oy + row, gx = ox + col;
        const bool v = ((unsigned)gy < (unsigned)Hn) && ((unsigned)gx < (unsigned)Wn);
        const size_t gidx = (size_t)b * 3 * HWn + gy * Wn + gx;
        float* dst = ptile3 + p * 3;
        dst[0] = v ? pf[gidx] : 0.f;
        dst[1] = v ? pf[gidx + HWn] : 0.f;
        dst[2] = v ? pf[gidx + 2 * HWn] : 0.f;
    }
    // ---- stage t8b: 8ch conv tile (halo 1), bf16-packed [pix][8ch] ----
    for (int p = tid; p < 324; p += 256) {
        const int row = p / 18;
        const int col = p - row * 18;
        const int gy = tileY0 + row - 1, gx = tileX0 + col - 1;
        const bool v = ((unsigned)gy < (unsigned)Hn) && ((unsigned)gx < (unsigned)Wn);
        const size_t base = (size_t)b * 3 * HWn + gy * Wn + gx;
        float c0 = v ? pf[base] : 0.f;
        float c1 = v ? pf[base + HWn] : 0.f;
        float c2 = v ? pf[base + 2 * HWn] : 0.f;
        float c3 = v ? cf[base] : 0.f;
        float c4 = v ? cf[base + HWn] : 0.f;
        float c5 = v ? cf[base + 2 * HWn] : 0.f;
        const size_t mbase = (size_t)b * 2 * HWn + gy * Wn + gx;
        float c6 = v ? mv[mbase] : 0.f;
        float c7 = v ? mv[mbase + HWn] : 0.f;
        union { unsigned u[4]; f32x4 f; } P;
        P.u[0] = (unsigned)rne_bf16(c0) | ((unsigned)rne_bf16(c1) << 16);
        P.u[1] = (unsigned)rne_bf16(c2) | ((unsigned)rne_bf16(c3) << 16);
        P.u[2] = (unsigned)rne_bf16(c4) | ((unsigned)rne_bf16(c5) << 16);
        P.u[3] = (unsigned)rne_bf16(c6) | ((unsigned)rne_bf16(c7) << 16);
        *(f32x4*)(t8b + p * 4) = P.f;
    }
    __syncthreads();

    // ---- MFMA GEMM [256 x 96] @ [96 x 32], C = bias ----
    f32x4 acc[4][2];
#pragma unroll
    for (int mt = 0; mt < 4; ++mt) {
        acc[mt][0] = (f32x4){bias0, bias0, bias0, bias0};
        acc[mt][1] = (f32x4){bias1, bias1, bias1, bias1};
    }

#pragma unroll
    for (int mt = 0; mt < 4; ++mt) {
        const int mrow = wv * 4 + mt;              // pixel row (ty)
#pragma unroll
        for (int s = 0; s < 3; ++s) {
            const int tap = 4 * s + g;             // this lane's tap
            const int tc  = tap < 9 ? tap : 8;     // pad taps: B=0, any A ok
            const int dy = tc / 3, dx = tc - dy * 3;
            union { f32x4 f; s16x8 v; } A;
            A.f = *(const f32x4*)(t8b + ((mrow + dy) * 18 + (am + dx)) * 4);
            acc[mt][0] = __builtin_amdgcn_mfma_f32_16x16x32_bf16(A.v, bfrag[s][0], acc[mt][0], 0, 0, 0);
            acc[mt][1] = __builtin_amdgcn_mfma_f32_16x16x32_bf16(A.v, bfrag[s][1], acc[mt][1], 0, 0, 0);
        }
    }
    __syncthreads();   // t8b reads done; region becomes offb

    // ---- redistribute D -> offb[pixel][oc], stride 19 (bias included) ----
    float* offb = smem + OFF_T8;
#pragma unroll
    for (int mt = 0; mt < 4; ++mt) {
        const int prow = wv * 4 + mt;
#pragma unroll
        for (int r = 0; r < 4; ++r) {
            const int pix = prow * 16 + (g * 4 + r);
            offb[pix * 19 + am] = acc[mt][0][r];
            if (am < 2) offb[pix * 19 + 16 + am] = acc[mt][1][r];
        }
    }
    __syncthreads();

    // ---- per-pixel offsets + stage-2 deformable conv ----
    const int tx = tid & 15;
    const int ty = tid >> 4;
    const int x = tileX0 + tx;
    const int y = tileY0 + ty;

    f32x2 offs2[9];
#pragma unroll
    for (int j = 0; j < 9; ++j) {
        offs2[j].x = offb[tid * 19 + 2 * j];
        offs2[j].y = offb[tid * 19 + 2 * j + 1];
    }

    const float* p0 = pf + (size_t)b * 3 * HWn;
    f32x2 accP = splat2(0.f);            // outputs 0,1
    float acc2c = 0.f;                   // output 2
    const float tyf = (float)(ty + PH - 1);
    const float txf = (float)(tx + PH - 1);

#pragma unroll
    for (int k = 0; k < 9; ++k) {
        const int ky = k / 3;
        const int kx = k - ky * 3;
        f32x2 basek;
        basek.x = tyf + (float)ky;
        basek.y = txf + (float)kx;
        const f32x2 pyx = offs2[k] + basek;          // tile-relative (y,x)
        const f32x2 fl = vfloor2(pyx);
        const f32x2 w  = pyx - fl;                   // (wy, wx)
        const int ty0 = (int)fl.x;
        const int tx0 = (int)fl.y;
        const float wy = w.x, wx = w.y;

        const bool inT = ((unsigned)ty0 < (unsigned)(PT - 1)) &&
                         ((unsigned)tx0 < (unsigned)(PT - 1));
        float s0, s1, s2;
        if (inT) {
            const float* base  = ptile3 + (ty0 * PT + tx0) * 3;
            const float* base2 = base + 3 * PT;
            const float a0 = base[0],  a1 = base[1],  a2 = base[2];   // q00
            const float b0 = base[3],  b1 = base[4],  b2 = base[5];   // q01
            const float c0 = base2[0], c1 = base2[1], c2 = base2[2];  // q10
            const float d0 = base2[3], d1 = base2[4], d2 = base2[5];  // q11
            f32x2 q00; q00.x = a0; q00.y = a1;
            f32x2 q01; q01.x = b0; q01.y = b1;
            f32x2 q10; q10.x = c0; q10.y = c1;
            f32x2 q11; q11.x = d0; q11.y = d1;
            const f32x2 wx2 = splat2(wx);
            const f32x2 wy2 = splat2(wy);
            const f32x2 h0 = vfma2(wx2, q01 - q00, q00);
            const f32x2 h1 = vfma2(wx2, q11 - q10, q10);
            const f32x2 s01 = vfma2(wy2, h1 - h0, h0);
            const float h0c = fmaf(wx, b2 - a2, a2);
            const float h1c = fmaf(wx, d2 - c2, c2);
            s0 = s01.x; s1 = s01.y;
            s2 = fmaf(wy, h1c - h0c, h0c);
        } else {
            const int y0 = ty0 + oy, x0 = tx0 + ox;
            const int y1 = y0 + 1,  x1 = x0 + 1;
            const bool vy0 = ((unsigned)y0 < (unsigned)Hn);
            const bool vy1 = ((unsigned)y1 < (unsigned)Hn);
            const bool vx0 = ((unsigned)x0 < (unsigned)Wn);
            const bool vx1 = ((unsigned)x1 < (unsigned)Wn);
            const int y0c = min(max(y0, 0), Hn - 1);
            const int y1c = min(max(y1, 0), Hn - 1);
            const int x0c = min(max(x0, 0), Wn - 1);
            const int x1c = min(max(x1, 0), Wn - 1);
            const int i00 = y0c * Wn + x0c;
            const int i01 = y0c * Wn + x1c;
            const int i10 = y1c * Wn + x0c;
            const int i11 = y1c * Wn + x1c;
            const float w00 = (1.f - wy) * (1.f - wx);
            const float w01 = (1.f - wy) * wx;
            const float w10 = wy * (1.f - wx);
            const float w11 = wy * wx;
            float sv[3];
#pragma unroll
            for (int i = 0; i < 3; ++i) {
                const float* pl = p0 + (size_t)i * HWn;
                const float v00 = (vy0 && vx0) ? pl[i00] : 0.f;
                const float v01 = (vy0 && vx1) ? pl[i01] : 0.f;
                const float v10 = (vy1 && vx0) ? pl[i10] : 0.f;
                const float v11 = (vy1 && vx1) ? pl[i11] : 0.f;
                sv[i] = w00 * v00 + w01 * v01 + w10 * v10 + w11 * v11;
            }
            s0 = sv[0]; s1 = sv[1]; s2 = sv[2];
        }
        // epilogue: acc[o] += dw[o][i][k] * s_i  (o pair packed, o=2 scalar)
        {
            f32x2 dwp0; dwp0.x = dw[0 * 27 + 0 * 9 + k]; dwp0.y = dw[1 * 27 + 0 * 9 + k];
            f32x2 dwp1; dwp1.x = dw[0 * 27 + 1 * 9 + k]; dwp1.y = dw[1 * 27 + 1 * 9 + k];
            f32x2 dwp2; dwp2.x = dw[0 * 27 + 2 * 9 + k]; dwp2.y = dw[1 * 27 + 2 * 9 + k];
            accP = vfma2(dwp0, splat2(s0), accP);
            accP = vfma2(dwp1, splat2(s1), accP);
            accP = vfma2(dwp2, splat2(s2), accP);
            acc2c = fmaf(dw[2 * 27 + 0 * 9 + k], s0, acc2c);
            acc2c = fmaf(dw[2 * 27 + 1 * 9 + k], s1, acc2c);
            acc2c = fmaf(dw[2 * 27 + 2 * 9 + k], s2, acc2c);
        }
    }

    const size_t obase = ((size_t)b * 3 * Hn + y) * Wn + x;
    out[obase] = accP.x;
    out[obase + HWn] = accP.y;
    out[obase + 2 * HWn] = acc2c;
}

extern "C" void kernel_launch(void* const* d_in, const int* in_sizes, int n_in,
                              void* d_out, int out_size, void* d_ws, size_t ws_size,
                              hipStream_t stream) {
    const float* pf = (const float*)d_in[0];
    const float* cf = (const float*)d_in[1];
    const float* mv = (const float*)d_in[2];
    const float* ow = (const float*)d_in[3];
    const float* ob = (const float*)d_in[4];
    const float* dw = (const float*)d_in[5];
    float* out = (float*)d_out;
    unsigned short* bwg = (unsigned short*)d_ws;   // 6*64*8 ushorts = 6 KB

    prep_bw<<<6, 64, 0, stream>>>(ow, bwg);
    dim3 grid(Wn / TILE, Hn / TILE, Bn);   // 24 x 24 x 8
    guided_cnn_fused<<<grid, 256, 0, stream>>>(pf, cf, mv, (const s16x8*)bwg, ob, dw, out);
}